// Round 10
// baseline (72.671 us; speedup 1.0000x reference)
//
#include <hip/hip_runtime.h>

#define N_NODES 1024
#define BATCH   128
#define E_DIM   16

// Operand panel format (bf16, per 128-row x 1024-k panel, 256KB):
//   elem(row, k) at  (k>>6)*8192 + ((k>>3)&7)*1024 + row*8 + (k&7)
// K-tile kt (BK=32) = shorts [kt*4096, kt*4096+4096) = 8 contiguous 1KB chunks.

typedef __attribute__((ext_vector_type(8))) short bf16x8;
typedef __attribute__((ext_vector_type(4))) float f32x4;
typedef __attribute__((ext_vector_type(16))) float f32x16;

__device__ __forceinline__ unsigned short f2bf(float f) {
    union { float f; unsigned int u; } v; v.f = f;
    unsigned int u = v.u;
    u += 0x7FFFu + ((u >> 16) & 1u);
    return (unsigned short)(u >> 16);
}

__device__ __forceinline__ void gload_lds16(const void* g, void* l) {
    __builtin_amdgcn_global_load_lds(
        (const __attribute__((address_space(1))) unsigned int*)g,
        (__attribute__((address_space(3))) unsigned int*)l, 16, 0, 0);
}

// ---------------- A: supports = softmax(relu(emb emb^T)) -> bf16 tiled ------
__global__ __launch_bounds__(256) void k_supports(const float* __restrict__ emb,
                                                  unsigned short* __restrict__ sup) {
    const int n = blockIdx.x;
    const int t = threadIdx.x;
    __shared__ float en[E_DIM];
    __shared__ float red[4];
    if (t < E_DIM) en[t] = emb[n * E_DIM + t];
    __syncthreads();

    float sc[4];
    float mx = -1e30f;
#pragma unroll
    for (int r = 0; r < 4; ++r) {
        const float* em = &emb[(r * 256 + t) * E_DIM];
        float s = 0.f;
#pragma unroll
        for (int e = 0; e < E_DIM; ++e) s = fmaf(en[e], em[e], s);
        s = fmaxf(s, 0.f);
        sc[r] = s;
        mx = fmaxf(mx, s);
    }
#pragma unroll
    for (int o = 32; o > 0; o >>= 1) mx = fmaxf(mx, __shfl_xor(mx, o));
    if ((t & 63) == 0) red[t >> 6] = mx;
    __syncthreads();
    mx = fmaxf(fmaxf(red[0], red[1]), fmaxf(red[2], red[3]));

    float sum = 0.f;
#pragma unroll
    for (int r = 0; r < 4; ++r) { sc[r] = __expf(sc[r] - mx); sum += sc[r]; }
#pragma unroll
    for (int o = 32; o > 0; o >>= 1) sum += __shfl_xor(sum, o);
    __syncthreads();
    if ((t & 63) == 0) red[t >> 6] = sum;
    __syncthreads();
    sum = red[0] + red[1] + red[2] + red[3];
    const float inv = 1.f / sum;
#pragma unroll
    for (int r = 0; r < 4; ++r) {
        const int m = r * 256 + t;
        const int off = (n >> 7) * 131072 + (m >> 6) * 8192 + ((m >> 3) & 7) * 1024
                      + (n & 127) * 8 + (m & 7);
        sup[off] = f2bf(sc[r] * inv);
    }
}

// ---------------- B: xbt tiled panels; j = b*64+c, k = m --------------------
__global__ __launch_bounds__(256) void k_xt(const float* __restrict__ x,
                                            unsigned short* __restrict__ xbt) {
    __shared__ __align__(16) unsigned short xt[64 * 72];   // [c][m], pitch 72
    const int t  = threadIdx.x;
    const int b  = blockIdx.y;
    const int m0 = blockIdx.x * 64;                        // kt64 = blockIdx.x
    const int c  = t & 63, mr = t >> 6;
    const float* src = x + ((long)b * N_NODES + m0 + mr) * 64 + c;
#pragma unroll
    for (int i = 0; i < 16; ++i)
        xt[c * 72 + mr + i * 4] = f2bf(src[(long)i * 4 * 64]);
    __syncthreads();
    const int cc = t >> 2, mb = (t & 3) * 16;              // 16 m per thread
    const int p  = b >> 1, jr = (b & 1) * 64 + cc;         // panel, row-in-panel
    unsigned short* dst = xbt + (long)p * 131072 + (long)blockIdx.x * 8192 + jr * 8;
    *(bf16x8*)(dst + ((t & 3) * 2 + 0) * 1024) = *(const bf16x8*)(&xt[cc * 72 + mb]);
    *(bf16x8*)(dst + ((t & 3) * 2 + 1) * 1024) = *(const bf16x8*)(&xt[cc * 72 + mb + 8]);
}

// ---------------- C: Wt per-node tiled, 4 nodes/block (48KB LDS) ------------
__global__ __launch_bounds__(256) void k_weights(const float* __restrict__ emb,
                                                 const float* __restrict__ wpool,
                                                 const float* __restrict__ bpool,
                                                 unsigned short* __restrict__ Wt,
                                                 float* __restrict__ bias) {
    const int t  = threadIdx.x;
    const int n0 = blockIdx.x * 4;       // 256 blocks
    __shared__ float en[4][E_DIM];
    __shared__ float wl[E_DIM * 256];                       // 16KB
    __shared__ __align__(16) unsigned short st[4 * 4096];   // 32KB
    if (t < 64) en[t >> 4][t & 15] = emb[(n0 + (t >> 4)) * E_DIM + (t & 15)];
    __syncthreads();

    for (int c = 0; c < 16; ++c) {
#pragma unroll
        for (int e = 0; e < E_DIM; ++e) wl[e * 256 + t] = wpool[e * 4096 + c * 256 + t];
        __syncthreads();
        // idx = c*256+t = i*64+o ; tiled dst d2 = (i>>3)*512 + o*8 + (i&7)
        //   i = c*4 + (t>>6), o = t&63  ->  kblk = c>>1, e = (c&1)*4 + (t>>6)
        const int d2 = (c >> 1) * 512 + (t & 63) * 8 + (c & 1) * 4 + (t >> 6);
#pragma unroll
        for (int nn = 0; nn < 4; ++nn) {
            float s = 0.f;
#pragma unroll
            for (int e = 0; e < E_DIM; ++e) s = fmaf(en[nn][e], wl[e * 256 + t], s);
            st[nn * 4096 + d2] = f2bf(s);
        }
        __syncthreads();
    }
    {   // bias: 4 nodes x 64 o
        const int nn = t >> 6, o = t & 63;
        float s = 0.f;
#pragma unroll
        for (int e = 0; e < E_DIM; ++e) s = fmaf(en[nn][e], bpool[e * 64 + o], s);
        bias[(n0 + nn) * 64 + o] = s;
    }
    // coalesced write-out: 4 nodes x 4096 shorts = 2048 granules of 16B
#pragma unroll
    for (int r = 0; r < 8; ++r) {
        const int q = r * 256 + t;           // 0..2047
        *(bf16x8*)(Wt + (long)n0 * 4096 + q * 8) = *(const bf16x8*)&st[q * 8];
    }
}

// ---------------- D: xg = S @ X, 128x128, BK=32, 1-barrier/iter pipeline ----
__global__ __launch_bounds__(256, 2) void k_agg(const unsigned short* __restrict__ S,
                                                const unsigned short* __restrict__ Bt,
                                                unsigned short* __restrict__ xg) {
    __shared__ __align__(16) char lds[65536];   // 4 buffers x 16KB
    const int t = threadIdx.x;
    const int lane = t & 63, wid = t >> 6;

    // bijective XCD swizzle: 512 blocks, 8 XCDs, 64 blocks per XCD chunk
    const int hw   = blockIdx.x + 8 * blockIdx.y;      // grid (8, 64)
    const int work = (hw & 7) * 64 + (hw >> 3);
    const int n0 = (work & 7) * 128, j0 = (work >> 3) * 128;
    const int wr = wid >> 1, wc = wid & 1;

    f32x16 acc[2][2];
#pragma unroll
    for (int m = 0; m < 2; ++m)
#pragma unroll
        for (int n = 0; n < 2; ++n)
#pragma unroll
            for (int r = 0; r < 16; ++r) acc[m][n][r] = 0.f;

    // 16 contiguous 1KB chunks per K-tile (8 A + 8 B); wave owns 4
    const unsigned short* pA = S  + (n0 >> 7) * 131072 + lane * 8;
    const unsigned short* pB = Bt + (j0 >> 7) * 131072 + lane * 8;
    const unsigned short* sp[4];
    int doff[4];
#pragma unroll
    for (int i = 0; i < 4; ++i) {
        const int c = wid * 4 + i;
        if (c < 8) { sp[i] = pA + c * 512;       doff[i] = c * 1024; }
        else       { sp[i] = pB + (c - 8) * 512; doff[i] = 8192 + (c - 8) * 1024; }
    }
#define STAGE(kt) do {                                                   \
        char* buf_ = lds + ((kt) & 3) * 16384;                           \
        const int ko_ = (kt) * 4096;                                     \
        gload_lds16(sp[0] + ko_, buf_ + doff[0]);                        \
        gload_lds16(sp[1] + ko_, buf_ + doff[1]);                        \
        gload_lds16(sp[2] + ko_, buf_ + doff[2]);                        \
        gload_lds16(sp[3] + ko_, buf_ + doff[3]);                        \
    } while (0)

    // fragment offsets: kstep s (0..1) gives kblk = s*2 + (lane>>5)
    int aoff[2], boff[2];
#pragma unroll
    for (int m = 0; m < 2; ++m)
        aoff[m] = (lane >> 5) * 2048 + (wr * 64 + m * 32 + (lane & 31)) * 16;
#pragma unroll
    for (int n = 0; n < 2; ++n)
        boff[n] = 8192 + (lane >> 5) * 2048 + (wc * 64 + n * 32 + (lane & 31)) * 16;

    STAGE(0); STAGE(1);                    // 8 loads/wave in flight
    for (int kt = 0; kt < 32; ++kt) {
        // own-wave vmcnt BEFORE barrier: after barrier, ALL waves' kt-chunks done
        if (kt < 31) asm volatile("s_waitcnt vmcnt(4)" ::: "memory");
        else         asm volatile("s_waitcnt vmcnt(0)" ::: "memory");
        __builtin_amdgcn_s_barrier();
        asm volatile("" ::: "memory");     // IR fence: no LDS access hoists above
        __builtin_amdgcn_sched_barrier(0); // MIR fence
        // buf[(kt+2)&3] last READ at iter kt-2; readers' MFMAs retired those
        // ds_reads (lgkmcnt) before crossing barriers kt-1 and kt -> WAR safe.
        if (kt + 2 < 32) STAGE(kt + 2);
        const char* cur = lds + (kt & 3) * 16384;
        __builtin_amdgcn_s_setprio(1);
#pragma unroll
        for (int s = 0; s < 2; ++s) {
            bf16x8 a[2], b[2];
#pragma unroll
            for (int m = 0; m < 2; ++m) a[m] = *(const bf16x8*)(cur + s * 4096 + aoff[m]);
#pragma unroll
            for (int n = 0; n < 2; ++n) b[n] = *(const bf16x8*)(cur + s * 4096 + boff[n]);
#pragma unroll
            for (int m = 0; m < 2; ++m)
#pragma unroll
                for (int n = 0; n < 2; ++n)
                    acc[m][n] = __builtin_amdgcn_mfma_f32_32x32x16_bf16(a[m], b[n], acc[m][n], 0, 0, 0);
        }
        __builtin_amdgcn_s_setprio(0);
        asm volatile("" ::: "memory");
        __builtin_amdgcn_sched_barrier(0);
        // no second barrier: single resync per K-tile
    }
#undef STAGE
    __syncthreads();   // all reads done before epilogue reuses lds

    // epilogue: acc -> LDS bf16 [128 row][128 col] swizzled -> tiled xg
    // C layout (32x32): col = lane&31, row = (r&3) + 8*(r>>2) + 4*(lane>>5)
    char* lb = lds;
#pragma unroll
    for (int m = 0; m < 2; ++m) {
#pragma unroll
        for (int n = 0; n < 2; ++n) {
            const int col  = wc * 64 + n * 32 + (lane & 31);
            const int rowb = wr * 64 + m * 32 + 4 * (lane >> 5);
#pragma unroll
            for (int r = 0; r < 16; ++r) {
                const int row = rowb + (r & 3) + 8 * (r >> 2);
                *(unsigned short*)(lb + row * 256 + ((col * 2) ^ ((row & 7) << 4))) =
                    f2bf(acc[m][n][r]);
            }
        }
    }
    __syncthreads();
    // xg per-node tiled: node*8192 + (i>>3)*1024 + b*8 + (i&7); j = b*64+i
#pragma unroll
    for (int i = 0; i < 8; ++i) {
        const int idx = i * 256 + t;          // 2048 granules of 16B
        const int row = idx >> 4, cc = idx & 15;
        bf16x8 v = *(const bf16x8*)(lb + row * 256 + ((cc * 16) ^ ((row & 7) << 4)));
        const long dst = (long)(n0 + row) * 8192 + (cc & 7) * 1024
                       + ((j0 >> 6) + (cc >> 3)) * 8;
        *(bf16x8*)(xg + dst) = v;
    }
}

// ---------------- E: out[b,n,o] = xg_n[b,:] @ W_n + bias_n ------------------
__global__ __launch_bounds__(256) void k_out(const unsigned short* __restrict__ xg,
                                             const unsigned short* __restrict__ Wt,
                                             const float* __restrict__ bias,
                                             float* __restrict__ out) {
    __shared__ __align__(16) char lds[24576];   // xg_n 16KB | Wt_n 8KB
    const int t = threadIdx.x, lane = t & 63, wid = t >> 6;
    const int node = blockIdx.x;
    const unsigned short* gx = xg + (long)node * 8192;
    const unsigned short* gw = Wt + (long)node * 4096;
#pragma unroll
    for (int i = 0; i < 4; ++i) {
        const int c = wid * 4 + i;            // 0..15, contiguous 1KB chunks
        gload_lds16(gx + c * 512 + lane * 8, lds + c * 1024);
    }
#pragma unroll
    for (int i = 0; i < 2; ++i) {
        const int c = wid * 2 + i;            // 0..7
        gload_lds16(gw + c * 512 + lane * 8, lds + 16384 + c * 1024);
    }
    __syncthreads();

    f32x4 acc[2][4];
#pragma unroll
    for (int m = 0; m < 2; ++m)
#pragma unroll
        for (int n = 0; n < 4; ++n) acc[m][n] = f32x4{0.f, 0.f, 0.f, 0.f};

#pragma unroll
    for (int s = 0; s < 2; ++s) {
        const int kb = s * 4 + (lane >> 4);
        bf16x8 a[2], b[4];
#pragma unroll
        for (int m = 0; m < 2; ++m)
            a[m] = *(const bf16x8*)(lds + kb * 2048 + (wid * 32 + m * 16 + (lane & 15)) * 16);
#pragma unroll
        for (int n = 0; n < 4; ++n)
            b[n] = *(const bf16x8*)(lds + 16384 + kb * 1024 + (n * 16 + (lane & 15)) * 16);
#pragma unroll
        for (int m = 0; m < 2; ++m)
#pragma unroll
            for (int n = 0; n < 4; ++n)
                acc[m][n] = __builtin_amdgcn_mfma_f32_16x16x32_bf16(a[m], b[n], acc[m][n], 0, 0, 0);
    }

#pragma unroll
    for (int n = 0; n < 4; ++n) {
        const int o = n * 16 + (lane & 15);
        const float bv = bias[node * 64 + o];
#pragma unroll
        for (int m = 0; m < 2; ++m) {
            const int b0 = wid * 32 + m * 16 + (lane >> 4) * 4;
#pragma unroll
            for (int r = 0; r < 4; ++r)
                out[(long)(b0 + r) * 65536 + node * 64 + o] = acc[m][n][r] + bv;
        }
    }
}

extern "C" void kernel_launch(void* const* d_in, const int* in_sizes, int n_in,
                              void* d_out, int out_size, void* d_ws, size_t ws_size,
                              hipStream_t stream) {
    const float* x     = (const float*)d_in[0];
    const float* emb   = (const float*)d_in[1];
    const float* wpool = (const float*)d_in[2];
    const float* bpool = (const float*)d_in[3];
    float* out = (float*)d_out;

    char* ws = (char*)d_ws;
    unsigned short* sup  = (unsigned short*)(ws);                        // 2 MiB
    unsigned short* xbt  = (unsigned short*)(ws + (2u  << 20));          // 16 MiB
    unsigned short* Wt   = (unsigned short*)(ws + (18u << 20));          // 8 MiB
    float*          bias = (float*)         (ws + (26u << 20));          // 256 KiB
    unsigned short* xg   = (unsigned short*)(ws + (27u << 20));          // 16 MiB
    (void)in_sizes; (void)n_in; (void)out_size; (void)ws_size;

    k_supports<<<dim3(N_NODES), dim3(256), 0, stream>>>(emb, sup);
    k_xt<<<dim3(16, BATCH), dim3(256), 0, stream>>>(x, xbt);
    k_weights<<<dim3(256), dim3(256), 0, stream>>>(emb, wpool, bpool, Wt, bias);
    k_agg<<<dim3(8, 64), dim3(256), 0, stream>>>(sup, xbt, xg);
    k_out<<<dim3(N_NODES), dim3(256), 0, stream>>>(xg, Wt, bias, out);
}

// Round 11
// 68.488 us; speedup vs baseline: 1.0611x; 1.0611x over previous
//
#include <hip/hip_runtime.h>

#define N_NODES 1024
#define BATCH   128
#define E_DIM   16

// Operand panel format (bf16, per 128-row x 1024-k panel, 256KB):
//   elem(row, k) at  (k>>6)*8192 + ((k>>3)&7)*1024 + row*8 + (k&7)
// K-tile kt (BK=32) = shorts [kt*4096, kt*4096+4096) = 8 contiguous 1KB chunks.

typedef __attribute__((ext_vector_type(8))) short bf16x8;
typedef __attribute__((ext_vector_type(4))) float f32x4;
typedef __attribute__((ext_vector_type(16))) float f32x16;

__device__ __forceinline__ unsigned short f2bf(float f) {
    union { float f; unsigned int u; } v; v.f = f;
    unsigned int u = v.u;
    u += 0x7FFFu + ((u >> 16) & 1u);
    return (unsigned short)(u >> 16);
}

__device__ __forceinline__ void gload_lds16(const void* g, void* l) {
    __builtin_amdgcn_global_load_lds(
        (const __attribute__((address_space(1))) unsigned int*)g,
        (__attribute__((address_space(3))) unsigned int*)l, 16, 0, 0);
}

// ---------------- P: fused producers (xt | weights | supports) --------------
__global__ __launch_bounds__(256) void k_prep(const float* __restrict__ x,
                                              const float* __restrict__ emb,
                                              const float* __restrict__ wpool,
                                              const float* __restrict__ bpool,
                                              unsigned short* __restrict__ xbt,
                                              unsigned short* __restrict__ sup,
                                              unsigned short* __restrict__ Wt,
                                              float* __restrict__ bias) {
    __shared__ __align__(16) char smem[49408];
    const int bid = blockIdx.x;
    const int t = threadIdx.x;

    if (bid < 2048) {
        // ---- xt: xbt tiled panels; j = b*64+c, k = m (verified R6) ----
        unsigned short* xt = (unsigned short*)smem;            // [64][72]
        const int b  = bid >> 4;
        const int kt64 = bid & 15;
        const int m0 = kt64 * 64;
        const int c  = t & 63, mr = t >> 6;
        const float* src = x + ((long)b * N_NODES + m0 + mr) * 64 + c;
#pragma unroll
        for (int i = 0; i < 16; ++i)
            xt[c * 72 + mr + i * 4] = f2bf(src[(long)i * 4 * 64]);
        __syncthreads();
        const int cc = t >> 2, mb = (t & 3) * 16;
        const int p  = b >> 1, jr = (b & 1) * 64 + cc;
        unsigned short* dst = xbt + (long)p * 131072 + (long)kt64 * 8192 + jr * 8;
        *(bf16x8*)(dst + ((t & 3) * 2 + 0) * 1024) = *(const bf16x8*)(&xt[cc * 72 + mb]);
        *(bf16x8*)(dst + ((t & 3) * 2 + 1) * 1024) = *(const bf16x8*)(&xt[cc * 72 + mb + 8]);
    } else if (bid < 2304) {
        // ---- weights: Wt per-node tiled, 4 nodes/block (verified R10) ----
        float (*en)[E_DIM] = (float(*)[E_DIM])smem;                    // 256B
        float* wl = (float*)(smem + 256);                              // 16KB
        unsigned short* st = (unsigned short*)(smem + 256 + 16384);    // 32KB
        const int n0 = (bid - 2048) * 4;
        if (t < 64) en[t >> 4][t & 15] = emb[(n0 + (t >> 4)) * E_DIM + (t & 15)];
        __syncthreads();
        for (int c = 0; c < 16; ++c) {
#pragma unroll
            for (int e = 0; e < E_DIM; ++e) wl[e * 256 + t] = wpool[e * 4096 + c * 256 + t];
            __syncthreads();
            const int d2 = (c >> 1) * 512 + (t & 63) * 8 + (c & 1) * 4 + (t >> 6);
#pragma unroll
            for (int nn = 0; nn < 4; ++nn) {
                float s = 0.f;
#pragma unroll
                for (int e = 0; e < E_DIM; ++e) s = fmaf(en[nn][e], wl[e * 256 + t], s);
                st[nn * 4096 + d2] = f2bf(s);
            }
            __syncthreads();
        }
        {
            const int nn = t >> 6, o = t & 63;
            float s = 0.f;
#pragma unroll
            for (int e = 0; e < E_DIM; ++e) s = fmaf(en[nn][e], bpool[e * 64 + o], s);
            bias[(n0 + nn) * 64 + o] = s;
        }
#pragma unroll
        for (int r = 0; r < 8; ++r) {
            const int q = r * 256 + t;
            *(bf16x8*)(Wt + (long)n0 * 4096 + q * 8) = *(const bf16x8*)&st[q * 8];
        }
    } else {
        // ---- supports: softmax(relu(emb emb^T)) row, tiled (verified R6) ----
        float* en  = (float*)smem;            // 64B
        float* red = (float*)(smem + 64);     // 16B
        const int n = bid - 2304;
        if (t < E_DIM) en[t] = emb[n * E_DIM + t];
        __syncthreads();
        float sc[4];
        float mx = -1e30f;
#pragma unroll
        for (int r = 0; r < 4; ++r) {
            const float* em = &emb[(r * 256 + t) * E_DIM];
            float s = 0.f;
#pragma unroll
            for (int e = 0; e < E_DIM; ++e) s = fmaf(en[e], em[e], s);
            s = fmaxf(s, 0.f);
            sc[r] = s;
            mx = fmaxf(mx, s);
        }
#pragma unroll
        for (int o = 32; o > 0; o >>= 1) mx = fmaxf(mx, __shfl_xor(mx, o));
        if ((t & 63) == 0) red[t >> 6] = mx;
        __syncthreads();
        mx = fmaxf(fmaxf(red[0], red[1]), fmaxf(red[2], red[3]));
        float sum = 0.f;
#pragma unroll
        for (int r = 0; r < 4; ++r) { sc[r] = __expf(sc[r] - mx); sum += sc[r]; }
#pragma unroll
        for (int o = 32; o > 0; o >>= 1) sum += __shfl_xor(sum, o);
        __syncthreads();
        if ((t & 63) == 0) red[t >> 6] = sum;
        __syncthreads();
        sum = red[0] + red[1] + red[2] + red[3];
        const float inv = 1.f / sum;
#pragma unroll
        for (int r = 0; r < 4; ++r) {
            const int m = r * 256 + t;
            const int off = (n >> 7) * 131072 + (m >> 6) * 8192 + ((m >> 3) & 7) * 1024
                          + (n & 127) * 8 + (m & 7);
            sup[off] = f2bf(sc[r] * inv);
        }
    }
}

// ---------------- D: xg = S @ X, 128x128, BK=32, 1-barrier/iter (R10) -------
__global__ __launch_bounds__(256, 2) void k_agg(const unsigned short* __restrict__ S,
                                                const unsigned short* __restrict__ Bt,
                                                unsigned short* __restrict__ xg) {
    __shared__ __align__(16) char lds[65536];   // 4 buffers x 16KB
    const int t = threadIdx.x;
    const int lane = t & 63, wid = t >> 6;

    const int hw   = blockIdx.x + 8 * blockIdx.y;      // grid (8, 64)
    const int work = (hw & 7) * 64 + (hw >> 3);
    const int n0 = (work & 7) * 128, j0 = (work >> 3) * 128;
    const int wr = wid >> 1, wc = wid & 1;

    f32x16 acc[2][2];
#pragma unroll
    for (int m = 0; m < 2; ++m)
#pragma unroll
        for (int n = 0; n < 2; ++n)
#pragma unroll
            for (int r = 0; r < 16; ++r) acc[m][n][r] = 0.f;

    const unsigned short* pA = S  + (n0 >> 7) * 131072 + lane * 8;
    const unsigned short* pB = Bt + (j0 >> 7) * 131072 + lane * 8;
    const unsigned short* sp[4];
    int doff[4];
#pragma unroll
    for (int i = 0; i < 4; ++i) {
        const int c = wid * 4 + i;
        if (c < 8) { sp[i] = pA + c * 512;       doff[i] = c * 1024; }
        else       { sp[i] = pB + (c - 8) * 512; doff[i] = 8192 + (c - 8) * 1024; }
    }
#define STAGE(kt) do {                                                   \
        char* buf_ = lds + ((kt) & 3) * 16384;                           \
        const int ko_ = (kt) * 4096;                                     \
        gload_lds16(sp[0] + ko_, buf_ + doff[0]);                        \
        gload_lds16(sp[1] + ko_, buf_ + doff[1]);                        \
        gload_lds16(sp[2] + ko_, buf_ + doff[2]);                        \
        gload_lds16(sp[3] + ko_, buf_ + doff[3]);                        \
    } while (0)

    int aoff[2], boff[2];
#pragma unroll
    for (int m = 0; m < 2; ++m)
        aoff[m] = (lane >> 5) * 2048 + (wr * 64 + m * 32 + (lane & 31)) * 16;
#pragma unroll
    for (int n = 0; n < 2; ++n)
        boff[n] = 8192 + (lane >> 5) * 2048 + (wc * 64 + n * 32 + (lane & 31)) * 16;

    STAGE(0); STAGE(1);
    for (int kt = 0; kt < 32; ++kt) {
        if (kt < 31) asm volatile("s_waitcnt vmcnt(4)" ::: "memory");
        else         asm volatile("s_waitcnt vmcnt(0)" ::: "memory");
        __builtin_amdgcn_s_barrier();
        asm volatile("" ::: "memory");
        __builtin_amdgcn_sched_barrier(0);
        if (kt + 2 < 32) STAGE(kt + 2);
        const char* cur = lds + (kt & 3) * 16384;
        __builtin_amdgcn_s_setprio(1);
#pragma unroll
        for (int s = 0; s < 2; ++s) {
            bf16x8 a[2], b[2];
#pragma unroll
            for (int m = 0; m < 2; ++m) a[m] = *(const bf16x8*)(cur + s * 4096 + aoff[m]);
#pragma unroll
            for (int n = 0; n < 2; ++n) b[n] = *(const bf16x8*)(cur + s * 4096 + boff[n]);
#pragma unroll
            for (int m = 0; m < 2; ++m)
#pragma unroll
                for (int n = 0; n < 2; ++n)
                    acc[m][n] = __builtin_amdgcn_mfma_f32_32x32x16_bf16(a[m], b[n], acc[m][n], 0, 0, 0);
        }
        __builtin_amdgcn_s_setprio(0);
        asm volatile("" ::: "memory");
        __builtin_amdgcn_sched_barrier(0);
    }
#undef STAGE
    __syncthreads();

    char* lb = lds;
#pragma unroll
    for (int m = 0; m < 2; ++m) {
#pragma unroll
        for (int n = 0; n < 2; ++n) {
            const int col  = wc * 64 + n * 32 + (lane & 31);
            const int rowb = wr * 64 + m * 32 + 4 * (lane >> 5);
#pragma unroll
            for (int r = 0; r < 16; ++r) {
                const int row = rowb + (r & 3) + 8 * (r >> 2);
                *(unsigned short*)(lb + row * 256 + ((col * 2) ^ ((row & 7) << 4))) =
                    f2bf(acc[m][n][r]);
            }
        }
    }
    __syncthreads();
#pragma unroll
    for (int i = 0; i < 8; ++i) {
        const int idx = i * 256 + t;
        const int row = idx >> 4, cc = idx & 15;
        bf16x8 v = *(const bf16x8*)(lb + row * 256 + ((cc * 16) ^ ((row & 7) << 4)));
        const long dst = (long)(n0 + row) * 8192 + (cc & 7) * 1024
                       + ((j0 >> 6) + (cc >> 3)) * 8;
        *(bf16x8*)(xg + dst) = v;
    }
}

// ---------------- E: out, 2 nodes per block ---------------------------------
__global__ __launch_bounds__(256) void k_out(const unsigned short* __restrict__ xg,
                                             const unsigned short* __restrict__ Wt,
                                             const float* __restrict__ bias,
                                             float* __restrict__ out) {
    // LDS: [node0 xg 16KB][node1 xg 16KB][node0 Wt 8KB][node1 Wt 8KB]
    __shared__ __align__(16) char lds[49152];
    const int t = threadIdx.x, lane = t & 63, wid = t >> 6;
    const int nb = blockIdx.x * 2;
#pragma unroll
    for (int i = 0; i < 12; ++i) {
        const int c = wid * 12 + i;            // 0..47 contiguous 1KB chunks
        if (c < 32) {
            const int nn = c >> 4, k = c & 15;
            gload_lds16(xg + (long)(nb + nn) * 8192 + k * 512 + lane * 8,
                        lds + nn * 16384 + k * 1024);
        } else {
            const int cc = c - 32, nn = cc >> 3, k = cc & 7;
            gload_lds16(Wt + (long)(nb + nn) * 4096 + k * 512 + lane * 8,
                        lds + 32768 + nn * 8192 + k * 1024);
        }
    }
    __syncthreads();

    const int node = nb + (wid >> 1);          // waves 0-1: node0, 2-3: node1
    const int bh   = wid & 1;                  // b-half (64 rows)
    const char* xl = lds + (wid >> 1) * 16384;
    const char* wlp = lds + 32768 + (wid >> 1) * 8192;

    f32x4 acc[4][4];
#pragma unroll
    for (int m = 0; m < 4; ++m)
#pragma unroll
        for (int n = 0; n < 4; ++n) acc[m][n] = f32x4{0.f, 0.f, 0.f, 0.f};

#pragma unroll
    for (int s = 0; s < 2; ++s) {
        const int kb = s * 4 + (lane >> 4);
        bf16x8 a[4], b[4];
#pragma unroll
        for (int m = 0; m < 4; ++m)
            a[m] = *(const bf16x8*)(xl + kb * 2048 + (bh * 64 + m * 16 + (lane & 15)) * 16);
#pragma unroll
        for (int n = 0; n < 4; ++n)
            b[n] = *(const bf16x8*)(wlp + kb * 1024 + (n * 16 + (lane & 15)) * 16);
#pragma unroll
        for (int m = 0; m < 4; ++m)
#pragma unroll
            for (int n = 0; n < 4; ++n)
                acc[m][n] = __builtin_amdgcn_mfma_f32_16x16x32_bf16(a[m], b[n], acc[m][n], 0, 0, 0);
    }

#pragma unroll
    for (int n = 0; n < 4; ++n) {
        const int o = n * 16 + (lane & 15);
        const float bv = bias[node * 64 + o];
#pragma unroll
        for (int m = 0; m < 4; ++m) {
            const int b0 = bh * 64 + m * 16 + (lane >> 4) * 4;
#pragma unroll
            for (int r = 0; r < 4; ++r)
                out[(long)(b0 + r) * 65536 + node * 64 + o] = acc[m][n][r] + bv;
        }
    }
}

extern "C" void kernel_launch(void* const* d_in, const int* in_sizes, int n_in,
                              void* d_out, int out_size, void* d_ws, size_t ws_size,
                              hipStream_t stream) {
    const float* x     = (const float*)d_in[0];
    const float* emb   = (const float*)d_in[1];
    const float* wpool = (const float*)d_in[2];
    const float* bpool = (const float*)d_in[3];
    float* out = (float*)d_out;

    char* ws = (char*)d_ws;
    unsigned short* sup  = (unsigned short*)(ws);                        // 2 MiB
    unsigned short* xbt  = (unsigned short*)(ws + (2u  << 20));          // 16 MiB
    unsigned short* Wt   = (unsigned short*)(ws + (18u << 20));          // 8 MiB
    float*          bias = (float*)         (ws + (26u << 20));          // 256 KiB
    unsigned short* xg   = (unsigned short*)(ws + (27u << 20));          // 16 MiB
    (void)in_sizes; (void)n_in; (void)out_size; (void)ws_size;

    k_prep<<<dim3(3328), dim3(256), 0, stream>>>(x, emb, wpool, bpool,
                                                 xbt, sup, Wt, bias);
    k_agg<<<dim3(8, 64), dim3(256), 0, stream>>>(sup, xbt, xg);
    k_out<<<dim3(512), dim3(256), 0, stream>>>(xg, Wt, bias, out);
}

// Round 12
// 67.884 us; speedup vs baseline: 1.0705x; 1.0089x over previous
//
#include <hip/hip_runtime.h>

#define N_NODES 1024
#define BATCH   128
#define E_DIM   16

// S / xbt panel format (bf16, per 128-row x 1024-k panel, 256KB):
//   elem(row, k) at (k>>6)*8192 + ((k>>3)&7)*1024 + row*8 + (k&7)
// xg layout (node-major, swizzled): short off =
//   node*8192 + b*64 + ((ib ^ (b&7))*8 + e)   where i = ib*8+e  (i = D_IN ch)

typedef __attribute__((ext_vector_type(8))) short bf16x8;
typedef __attribute__((ext_vector_type(4))) float f32x4;
typedef __attribute__((ext_vector_type(16))) float f32x16;

__device__ __forceinline__ unsigned short f2bf(float f) {
    union { float f; unsigned int u; } v; v.f = f;
    unsigned int u = v.u;
    u += 0x7FFFu + ((u >> 16) & 1u);
    return (unsigned short)(u >> 16);
}

__device__ __forceinline__ void gload_lds16(const void* g, void* l) {
    __builtin_amdgcn_global_load_lds(
        (const __attribute__((address_space(1))) unsigned int*)g,
        (__attribute__((address_space(3))) unsigned int*)l, 16, 0, 0);
}

// ---------------- P: fused producers (xt | weights | supports) --------------
__global__ __launch_bounds__(256) void k_prep(const float* __restrict__ x,
                                              const float* __restrict__ emb,
                                              const float* __restrict__ wpool,
                                              const float* __restrict__ bpool,
                                              unsigned short* __restrict__ xbt,
                                              unsigned short* __restrict__ sup,
                                              unsigned short* __restrict__ Wt,
                                              float* __restrict__ bias) {
    __shared__ __align__(16) char smem[49408];
    const int bid = blockIdx.x;
    const int t = threadIdx.x;

    if (bid < 2048) {
        // ---- xt: register-only transpose, both sides coalesced ----
        // block = (b, kt64); granule g=(kblk,c): reads 8 floats stride-64,
        // lanes have consecutive c -> 256B coalesced loads; stores contiguous.
        const int b = bid >> 4, kt64 = bid & 15;
        unsigned short* dstp = xbt + (long)(b >> 1) * 131072 + kt64 * 8192
                             + (b & 1) * 512;          // + kblk*1024 + c*8
#pragma unroll
        for (int h = 0; h < 2; ++h) {
            const int g = h * 256 + t;                 // 0..511
            const int kblk = g >> 6, c = g & 63;
            const float* s = x + ((long)b * 1024 + kt64 * 64 + kblk * 8) * 64 + c;
            bf16x8 r;
#pragma unroll
            for (int e = 0; e < 8; ++e) r[e] = (short)f2bf(s[e * 64]);
            *(bf16x8*)(dstp + kblk * 1024 + c * 8) = r;
        }
    } else if (bid < 2304) {
        // ---- weights: Wt per-node tiled, 4 nodes/block (verified R10) ----
        float (*en)[E_DIM] = (float(*)[E_DIM])smem;                    // 256B
        float* wl = (float*)(smem + 256);                              // 16KB
        unsigned short* st = (unsigned short*)(smem + 256 + 16384);    // 32KB
        const int n0 = (bid - 2048) * 4;
        if (t < 64) en[t >> 4][t & 15] = emb[(n0 + (t >> 4)) * E_DIM + (t & 15)];
        __syncthreads();
        for (int c = 0; c < 16; ++c) {
#pragma unroll
            for (int e = 0; e < E_DIM; ++e) wl[e * 256 + t] = wpool[e * 4096 + c * 256 + t];
            __syncthreads();
            const int d2 = (c >> 1) * 512 + (t & 63) * 8 + (c & 1) * 4 + (t >> 6);
#pragma unroll
            for (int nn = 0; nn < 4; ++nn) {
                float s = 0.f;
#pragma unroll
                for (int e = 0; e < E_DIM; ++e) s = fmaf(en[nn][e], wl[e * 256 + t], s);
                st[nn * 4096 + d2] = f2bf(s);
            }
            __syncthreads();
        }
        {
            const int nn = t >> 6, o = t & 63;
            float s = 0.f;
#pragma unroll
            for (int e = 0; e < E_DIM; ++e) s = fmaf(en[nn][e], bpool[e * 64 + o], s);
            bias[(n0 + nn) * 64 + o] = s;
        }
#pragma unroll
        for (int r = 0; r < 8; ++r) {
            const int q = r * 256 + t;
            *(bf16x8*)(Wt + (long)n0 * 4096 + q * 8) = *(const bf16x8*)&st[q * 8];
        }
    } else {
        // ---- supports: softmax(relu(emb emb^T)) row, tiled (verified R6) ----
        float* en  = (float*)smem;
        float* red = (float*)(smem + 64);
        const int n = bid - 2304;
        if (t < E_DIM) en[t] = emb[n * E_DIM + t];
        __syncthreads();
        float sc[4];
        float mx = -1e30f;
#pragma unroll
        for (int r = 0; r < 4; ++r) {
            const float* em = &emb[(r * 256 + t) * E_DIM];
            float s = 0.f;
#pragma unroll
            for (int e = 0; e < E_DIM; ++e) s = fmaf(en[e], em[e], s);
            s = fmaxf(s, 0.f);
            sc[r] = s;
            mx = fmaxf(mx, s);
        }
#pragma unroll
        for (int o = 32; o > 0; o >>= 1) mx = fmaxf(mx, __shfl_xor(mx, o));
        if ((t & 63) == 0) red[t >> 6] = mx;
        __syncthreads();
        mx = fmaxf(fmaxf(red[0], red[1]), fmaxf(red[2], red[3]));
        float sum = 0.f;
#pragma unroll
        for (int r = 0; r < 4; ++r) { sc[r] = __expf(sc[r] - mx); sum += sc[r]; }
#pragma unroll
        for (int o = 32; o > 0; o >>= 1) sum += __shfl_xor(sum, o);
        __syncthreads();
        if ((t & 63) == 0) red[t >> 6] = sum;
        __syncthreads();
        sum = red[0] + red[1] + red[2] + red[3];
        const float inv = 1.f / sum;
#pragma unroll
        for (int r = 0; r < 4; ++r) {
            const int m = r * 256 + t;
            const int off = (n >> 7) * 131072 + (m >> 6) * 8192 + ((m >> 3) & 7) * 1024
                          + (n & 127) * 8 + (m & 7);
            sup[off] = f2bf(sc[r] * inv);
        }
    }
}

// ---------------- D: xg = S @ X, 128x128, BK=32, 1-barrier/iter (R10) -------
__global__ __launch_bounds__(256, 2) void k_agg(const unsigned short* __restrict__ S,
                                                const unsigned short* __restrict__ Bt,
                                                unsigned short* __restrict__ xg) {
    __shared__ __align__(16) char lds[65536];   // 4 buffers x 16KB
    const int t = threadIdx.x;
    const int lane = t & 63, wid = t >> 6;

    const int hw   = blockIdx.x + 8 * blockIdx.y;      // grid (8, 64)
    const int work = (hw & 7) * 64 + (hw >> 3);
    const int n0 = (work & 7) * 128, j0 = (work >> 3) * 128;
    const int wr = wid >> 1, wc = wid & 1;

    f32x16 acc[2][2];
#pragma unroll
    for (int m = 0; m < 2; ++m)
#pragma unroll
        for (int n = 0; n < 2; ++n)
#pragma unroll
            for (int r = 0; r < 16; ++r) acc[m][n][r] = 0.f;

    const unsigned short* pA = S  + (n0 >> 7) * 131072 + lane * 8;
    const unsigned short* pB = Bt + (j0 >> 7) * 131072 + lane * 8;
    const unsigned short* sp[4];
    int doff[4];
#pragma unroll
    for (int i = 0; i < 4; ++i) {
        const int c = wid * 4 + i;
        if (c < 8) { sp[i] = pA + c * 512;       doff[i] = c * 1024; }
        else       { sp[i] = pB + (c - 8) * 512; doff[i] = 8192 + (c - 8) * 1024; }
    }
#define STAGE(kt) do {                                                   \
        char* buf_ = lds + ((kt) & 3) * 16384;                           \
        const int ko_ = (kt) * 4096;                                     \
        gload_lds16(sp[0] + ko_, buf_ + doff[0]);                        \
        gload_lds16(sp[1] + ko_, buf_ + doff[1]);                        \
        gload_lds16(sp[2] + ko_, buf_ + doff[2]);                        \
        gload_lds16(sp[3] + ko_, buf_ + doff[3]);                        \
    } while (0)

    int aoff[2], boff[2];
#pragma unroll
    for (int m = 0; m < 2; ++m)
        aoff[m] = (lane >> 5) * 2048 + (wr * 64 + m * 32 + (lane & 31)) * 16;
#pragma unroll
    for (int n = 0; n < 2; ++n)
        boff[n] = 8192 + (lane >> 5) * 2048 + (wc * 64 + n * 32 + (lane & 31)) * 16;

    STAGE(0); STAGE(1);
    for (int kt = 0; kt < 32; ++kt) {
        if (kt < 31) asm volatile("s_waitcnt vmcnt(4)" ::: "memory");
        else         asm volatile("s_waitcnt vmcnt(0)" ::: "memory");
        __builtin_amdgcn_s_barrier();
        asm volatile("" ::: "memory");
        __builtin_amdgcn_sched_barrier(0);
        if (kt + 2 < 32) STAGE(kt + 2);
        const char* cur = lds + (kt & 3) * 16384;
        __builtin_amdgcn_s_setprio(1);
#pragma unroll
        for (int s = 0; s < 2; ++s) {
            bf16x8 a[2], b[2];
#pragma unroll
            for (int m = 0; m < 2; ++m) a[m] = *(const bf16x8*)(cur + s * 4096 + aoff[m]);
#pragma unroll
            for (int n = 0; n < 2; ++n) b[n] = *(const bf16x8*)(cur + s * 4096 + boff[n]);
#pragma unroll
            for (int m = 0; m < 2; ++m)
#pragma unroll
                for (int n = 0; n < 2; ++n)
                    acc[m][n] = __builtin_amdgcn_mfma_f32_32x32x16_bf16(a[m], b[n], acc[m][n], 0, 0, 0);
        }
        __builtin_amdgcn_s_setprio(0);
        asm volatile("" ::: "memory");
        __builtin_amdgcn_sched_barrier(0);
    }
#undef STAGE
    __syncthreads();

    // epilogue: acc -> LDS bf16 [128 row][128 col] swizzled -> node-major xg
    char* lb = lds;
#pragma unroll
    for (int m = 0; m < 2; ++m) {
#pragma unroll
        for (int n = 0; n < 2; ++n) {
            const int col  = wc * 64 + n * 32 + (lane & 31);
            const int rowb = wr * 64 + m * 32 + 4 * (lane >> 5);
#pragma unroll
            for (int r = 0; r < 16; ++r) {
                const int row = rowb + (r & 3) + 8 * (r >> 2);
                *(unsigned short*)(lb + row * 256 + ((col * 2) ^ ((row & 7) << 4))) =
                    f2bf(acc[m][n][r]);
            }
        }
    }
    __syncthreads();
    // write: col = bsel*64 + i; b = b0+bsel; granule (node,b,ib) at
    // node*8192 + b*64 + (ib^(b&7))*8  -> 256B contiguous per row (2 b's)
    const int b0 = j0 >> 6;
#pragma unroll
    for (int i = 0; i < 8; ++i) {
        const int idx = i * 256 + t;          // 2048 granules of 16B
        const int row = idx >> 4, cc = idx & 15;
        bf16x8 v = *(const bf16x8*)(lb + row * 256 + ((cc * 16) ^ ((row & 7) << 4)));
        const int b = b0 + (cc >> 3);
        const long dst = (long)(n0 + row) * 8192 + b * 64 + ((cc & 7) ^ (b & 7)) * 8;
        *(bf16x8*)(xg + dst) = v;
    }
}

// ---------------- E: out, 2 nodes per block ---------------------------------
__global__ __launch_bounds__(256) void k_out(const unsigned short* __restrict__ xg,
                                             const unsigned short* __restrict__ Wt,
                                             const float* __restrict__ bias,
                                             float* __restrict__ out) {
    // LDS: [node0 xg 16KB][node1 xg 16KB][node0 Wt 8KB][node1 Wt 8KB]
    // xg LDS layout (linear copy of node slab): [b 128][ib^ (b&7)][8]
    __shared__ __align__(16) char lds[49152];
    const int t = threadIdx.x, lane = t & 63, wid = t >> 6;
    const int nb = blockIdx.x * 2;
#pragma unroll
    for (int i = 0; i < 12; ++i) {
        const int c = wid * 12 + i;            // 0..47 contiguous 1KB chunks
        if (c < 32) {
            const int nn = c >> 4, k = c & 15;
            gload_lds16(xg + (long)(nb + nn) * 8192 + k * 512 + lane * 8,
                        lds + nn * 16384 + k * 1024);
        } else {
            const int cc = c - 32, nn = cc >> 3, k = cc & 7;
            gload_lds16(Wt + (long)(nb + nn) * 4096 + k * 512 + lane * 8,
                        lds + 32768 + nn * 8192 + k * 1024);
        }
    }
    __syncthreads();

    const int node = nb + (wid >> 1);          // waves 0-1: node0, 2-3: node1
    const int bh   = wid & 1;                  // b-half (64 rows)
    const char* xl = lds + (wid >> 1) * 16384;
    const char* wlp = lds + 32768 + (wid >> 1) * 8192;

    f32x4 acc[4][4];
#pragma unroll
    for (int m = 0; m < 4; ++m)
#pragma unroll
        for (int n = 0; n < 4; ++n) acc[m][n] = f32x4{0.f, 0.f, 0.f, 0.f};

#pragma unroll
    for (int s = 0; s < 2; ++s) {
        const int kb = s * 4 + (lane >> 4);
        bf16x8 a[4], b[4];
#pragma unroll
        for (int m = 0; m < 4; ++m) {
            const int brow = bh * 64 + m * 16 + (lane & 15);
            a[m] = *(const bf16x8*)(xl + brow * 128 + ((kb ^ (lane & 7)) << 4));
        }
#pragma unroll
        for (int n = 0; n < 4; ++n)
            b[n] = *(const bf16x8*)(wlp + kb * 1024 + (n * 16 + (lane & 15)) * 16);
#pragma unroll
        for (int m = 0; m < 4; ++m)
#pragma unroll
            for (int n = 0; n < 4; ++n)
                acc[m][n] = __builtin_amdgcn_mfma_f32_16x16x32_bf16(a[m], b[n], acc[m][n], 0, 0, 0);
    }

#pragma unroll
    for (int n = 0; n < 4; ++n) {
        const int o = n * 16 + (lane & 15);
        const float bv = bias[node * 64 + o];
#pragma unroll
        for (int m = 0; m < 4; ++m) {
            const int b0 = bh * 64 + m * 16 + (lane >> 4) * 4;
#pragma unroll
            for (int r = 0; r < 4; ++r)
                out[(long)(b0 + r) * 65536 + node * 64 + o] = acc[m][n][r] + bv;
        }
    }
}

extern "C" void kernel_launch(void* const* d_in, const int* in_sizes, int n_in,
                              void* d_out, int out_size, void* d_ws, size_t ws_size,
                              hipStream_t stream) {
    const float* x     = (const float*)d_in[0];
    const float* emb   = (const float*)d_in[1];
    const float* wpool = (const float*)d_in[2];
    const float* bpool = (const float*)d_in[3];
    float* out = (float*)d_out;

    char* ws = (char*)d_ws;
    unsigned short* sup  = (unsigned short*)(ws);                        // 2 MiB
    unsigned short* xbt  = (unsigned short*)(ws + (2u  << 20));          // 16 MiB
    unsigned short* Wt   = (unsigned short*)(ws + (18u << 20));          // 8 MiB
    float*          bias = (float*)         (ws + (26u << 20));          // 256 KiB
    unsigned short* xg   = (unsigned short*)(ws + (27u << 20));          // 16 MiB
    (void)in_sizes; (void)n_in; (void)out_size; (void)ws_size;

    k_prep<<<dim3(3328), dim3(256), 0, stream>>>(x, emb, wpool, bpool,
                                                 xbt, sup, Wt, bias);
    k_agg<<<dim3(8, 64), dim3(256), 0, stream>>>(sup, xbt, xg);
    k_out<<<dim3(512), dim3(256), 0, stream>>>(xg, Wt, bias, out);
}

// Round 13
// 62.564 us; speedup vs baseline: 1.1615x; 1.0850x over previous
//
#include <hip/hip_runtime.h>

#define N_NODES 1024
#define BATCH   128
#define E_DIM   16

// S / xbt panel format (bf16, per 128-row x 1024-k panel, 256KB):
//   elem(row, k) at (k>>6)*8192 + ((k>>3)&7)*1024 + row*8 + (k&7)
// Wt per-node tiled: n*4096 + kblk*512 + o*8 + e   (i = kblk*8+e)
// xg layout (node-major, swizzled): short off =
//   node*8192 + b*64 + ((ib ^ (b&7))*8 + e)   where i = ib*8+e

typedef __attribute__((ext_vector_type(8))) short bf16x8;
typedef __attribute__((ext_vector_type(4))) float f32x4;
typedef __attribute__((ext_vector_type(16))) float f32x16;

__device__ __forceinline__ unsigned short f2bf(float f) {
    union { float f; unsigned int u; } v; v.f = f;
    unsigned int u = v.u;
    u += 0x7FFFu + ((u >> 16) & 1u);
    return (unsigned short)(u >> 16);
}

__device__ __forceinline__ void gload_lds16(const void* g, void* l) {
    __builtin_amdgcn_global_load_lds(
        (const __attribute__((address_space(1))) unsigned int*)g,
        (__attribute__((address_space(3))) unsigned int*)l, 16, 0, 0);
}

// ---------------- P: fused producers (xt | weights | supports) --------------
// grid: [0,2048) xt | [2048,2176) weights (8 nodes/blk) | [2176,3200) supports
__global__ __launch_bounds__(256) void k_prep(const float* __restrict__ x,
                                              const float* __restrict__ emb,
                                              const float* __restrict__ wpool,
                                              const float* __restrict__ bpool,
                                              unsigned short* __restrict__ xbt,
                                              unsigned short* __restrict__ sup,
                                              unsigned short* __restrict__ Wt,
                                              float* __restrict__ bias) {
    __shared__ float sm[132];    // weights: en8[8][16]; supports: en[16]+red[4]
    const int bid = blockIdx.x;
    const int t = threadIdx.x;

    if (bid < 2048) {
        // ---- xt: register-only transpose, both sides coalesced (R12) ----
        const int b = bid >> 4, kt64 = bid & 15;
        unsigned short* dstp = xbt + (long)(b >> 1) * 131072 + kt64 * 8192
                             + (b & 1) * 512;          // + kblk*1024 + c*8
#pragma unroll
        for (int h = 0; h < 2; ++h) {
            const int g = h * 256 + t;                 // 0..511
            const int kblk = g >> 6, c = g & 63;
            const float* s = x + ((long)b * 1024 + kt64 * 64 + kblk * 8) * 64 + c;
            bf16x8 r;
#pragma unroll
            for (int e = 0; e < 8; ++e) r[e] = (short)f2bf(s[e * 64]);
            *(bf16x8*)(dstp + kblk * 1024 + c * 8) = r;
        }
    } else if (bid < 2176) {
        // ---- weights: 8 nodes/block, register-direct, barrier-free ----
        float (*en8)[E_DIM] = (float(*)[E_DIM])sm;
        const int n0 = (bid - 2048) * 8;
        if (t < 128) en8[t >> 4][t & 15] = emb[(n0 + (t >> 4)) * E_DIM + (t & 15)];
        __syncthreads();
        const int o = t & 63;
#pragma unroll
        for (int p = 0; p < 2; ++p) {
            const int kblk = p * 4 + (t >> 6);
            float w[8][8];
#pragma unroll
            for (int nn = 0; nn < 8; ++nn)
#pragma unroll
                for (int e = 0; e < 8; ++e) w[nn][e] = 0.f;
            for (int ed = 0; ed < E_DIM; ++ed) {
                float v[8];
#pragma unroll
                for (int e = 0; e < 8; ++e)
                    v[e] = wpool[ed * 4096 + (kblk * 8 + e) * 64 + o];  // 256B coalesced
#pragma unroll
                for (int nn = 0; nn < 8; ++nn)
#pragma unroll
                    for (int e = 0; e < 8; ++e)
                        w[nn][e] = fmaf(en8[nn][ed], v[e], w[nn][e]);
            }
#pragma unroll
            for (int nn = 0; nn < 8; ++nn) {
                bf16x8 r;
#pragma unroll
                for (int e = 0; e < 8; ++e) r[e] = (short)f2bf(w[nn][e]);
                // lanes consecutive o -> contiguous 1KB per wave
                *(bf16x8*)(Wt + (long)(n0 + nn) * 4096 + kblk * 512 + o * 8) = r;
            }
        }
#pragma unroll
        for (int r2 = 0; r2 < 2; ++r2) {     // bias: 8 nodes x 64 o
            const int idx = r2 * 256 + t, nn = idx >> 6, oo = idx & 63;
            float s = 0.f;
#pragma unroll
            for (int e = 0; e < E_DIM; ++e) s = fmaf(en8[nn][e], bpool[e * 64 + oo], s);
            bias[(n0 + nn) * 64 + oo] = s;
        }
    } else {
        // ---- supports: softmax(relu(emb emb^T)) row, tiled (R6) ----
        float* en  = sm;
        float* red = sm + 128;
        const int n = bid - 2176;
        if (t < E_DIM) en[t] = emb[n * E_DIM + t];
        __syncthreads();
        float sc[4];
        float mx = -1e30f;
#pragma unroll
        for (int r = 0; r < 4; ++r) {
            const float* em = &emb[(r * 256 + t) * E_DIM];
            float s = 0.f;
#pragma unroll
            for (int e = 0; e < E_DIM; ++e) s = fmaf(en[e], em[e], s);
            s = fmaxf(s, 0.f);
            sc[r] = s;
            mx = fmaxf(mx, s);
        }
#pragma unroll
        for (int o = 32; o > 0; o >>= 1) mx = fmaxf(mx, __shfl_xor(mx, o));
        if ((t & 63) == 0) red[t >> 6] = mx;
        __syncthreads();
        mx = fmaxf(fmaxf(red[0], red[1]), fmaxf(red[2], red[3]));
        float sum = 0.f;
#pragma unroll
        for (int r = 0; r < 4; ++r) { sc[r] = __expf(sc[r] - mx); sum += sc[r]; }
#pragma unroll
        for (int o = 32; o > 0; o >>= 1) sum += __shfl_xor(sum, o);
        __syncthreads();
        if ((t & 63) == 0) red[t >> 6] = sum;
        __syncthreads();
        sum = red[0] + red[1] + red[2] + red[3];
        const float inv = 1.f / sum;
#pragma unroll
        for (int r = 0; r < 4; ++r) {
            const int m = r * 256 + t;
            const int off = (n >> 7) * 131072 + (m >> 6) * 8192 + ((m >> 3) & 7) * 1024
                          + (n & 127) * 8 + (m & 7);
            sup[off] = f2bf(sc[r] * inv);
        }
    }
}

// ---------------- D: xg = S @ X, 128x128, BK=32, 1-barrier/iter (R10) -------
__global__ __launch_bounds__(256, 2) void k_agg(const unsigned short* __restrict__ S,
                                                const unsigned short* __restrict__ Bt,
                                                unsigned short* __restrict__ xg) {
    __shared__ __align__(16) char lds[65536];   // 4 buffers x 16KB
    const int t = threadIdx.x;
    const int lane = t & 63, wid = t >> 6;

    const int hw   = blockIdx.x + 8 * blockIdx.y;      // grid (8, 64)
    const int work = (hw & 7) * 64 + (hw >> 3);
    const int n0 = (work & 7) * 128, j0 = (work >> 3) * 128;
    const int wr = wid >> 1, wc = wid & 1;

    f32x16 acc[2][2];
#pragma unroll
    for (int m = 0; m < 2; ++m)
#pragma unroll
        for (int n = 0; n < 2; ++n)
#pragma unroll
            for (int r = 0; r < 16; ++r) acc[m][n][r] = 0.f;

    const unsigned short* pA = S  + (n0 >> 7) * 131072 + lane * 8;
    const unsigned short* pB = Bt + (j0 >> 7) * 131072 + lane * 8;
    const unsigned short* sp[4];
    int doff[4];
#pragma unroll
    for (int i = 0; i < 4; ++i) {
        const int c = wid * 4 + i;
        if (c < 8) { sp[i] = pA + c * 512;       doff[i] = c * 1024; }
        else       { sp[i] = pB + (c - 8) * 512; doff[i] = 8192 + (c - 8) * 1024; }
    }
#define STAGE(kt) do {                                                   \
        char* buf_ = lds + ((kt) & 3) * 16384;                           \
        const int ko_ = (kt) * 4096;                                     \
        gload_lds16(sp[0] + ko_, buf_ + doff[0]);                        \
        gload_lds16(sp[1] + ko_, buf_ + doff[1]);                        \
        gload_lds16(sp[2] + ko_, buf_ + doff[2]);                        \
        gload_lds16(sp[3] + ko_, buf_ + doff[3]);                        \
    } while (0)

    int aoff[2], boff[2];
#pragma unroll
    for (int m = 0; m < 2; ++m)
        aoff[m] = (lane >> 5) * 2048 + (wr * 64 + m * 32 + (lane & 31)) * 16;
#pragma unroll
    for (int n = 0; n < 2; ++n)
        boff[n] = 8192 + (lane >> 5) * 2048 + (wc * 64 + n * 32 + (lane & 31)) * 16;

    STAGE(0); STAGE(1);
    for (int kt = 0; kt < 32; ++kt) {
        if (kt < 31) asm volatile("s_waitcnt vmcnt(4)" ::: "memory");
        else         asm volatile("s_waitcnt vmcnt(0)" ::: "memory");
        __builtin_amdgcn_s_barrier();
        asm volatile("" ::: "memory");
        __builtin_amdgcn_sched_barrier(0);
        if (kt + 2 < 32) STAGE(kt + 2);
        const char* cur = lds + (kt & 3) * 16384;
        __builtin_amdgcn_s_setprio(1);
#pragma unroll
        for (int s = 0; s < 2; ++s) {
            bf16x8 a[2], b[2];
#pragma unroll
            for (int m = 0; m < 2; ++m) a[m] = *(const bf16x8*)(cur + s * 4096 + aoff[m]);
#pragma unroll
            for (int n = 0; n < 2; ++n) b[n] = *(const bf16x8*)(cur + s * 4096 + boff[n]);
#pragma unroll
            for (int m = 0; m < 2; ++m)
#pragma unroll
                for (int n = 0; n < 2; ++n)
                    acc[m][n] = __builtin_amdgcn_mfma_f32_32x32x16_bf16(a[m], b[n], acc[m][n], 0, 0, 0);
        }
        __builtin_amdgcn_s_setprio(0);
        asm volatile("" ::: "memory");
        __builtin_amdgcn_sched_barrier(0);
    }
#undef STAGE
    __syncthreads();

    // epilogue: acc -> LDS bf16 [128 row][128 col] swizzled -> node-major xg
    char* lb = lds;
#pragma unroll
    for (int m = 0; m < 2; ++m) {
#pragma unroll
        for (int n = 0; n < 2; ++n) {
            const int col  = wc * 64 + n * 32 + (lane & 31);
            const int rowb = wr * 64 + m * 32 + 4 * (lane >> 5);
#pragma unroll
            for (int r = 0; r < 16; ++r) {
                const int row = rowb + (r & 3) + 8 * (r >> 2);
                *(unsigned short*)(lb + row * 256 + ((col * 2) ^ ((row & 7) << 4))) =
                    f2bf(acc[m][n][r]);
            }
        }
    }
    __syncthreads();
    const int b0 = j0 >> 6;
#pragma unroll
    for (int i = 0; i < 8; ++i) {
        const int idx = i * 256 + t;
        const int row = idx >> 4, cc = idx & 15;
        bf16x8 v = *(const bf16x8*)(lb + row * 256 + ((cc * 16) ^ ((row & 7) << 4)));
        const int b = b0 + (cc >> 3);
        const long dst = (long)(n0 + row) * 8192 + b * 64 + ((cc & 7) ^ (b & 7)) * 8;
        *(bf16x8*)(xg + dst) = v;
    }
}

// ---------------- E: out, 2 nodes per block ---------------------------------
__global__ __launch_bounds__(256) void k_out(const unsigned short* __restrict__ xg,
                                             const unsigned short* __restrict__ Wt,
                                             const float* __restrict__ bias,
                                             float* __restrict__ out) {
    __shared__ __align__(16) char lds[49152];
    const int t = threadIdx.x, lane = t & 63, wid = t >> 6;
    const int nb = blockIdx.x * 2;
#pragma unroll
    for (int i = 0; i < 12; ++i) {
        const int c = wid * 12 + i;            // 0..47 contiguous 1KB chunks
        if (c < 32) {
            const int nn = c >> 4, k = c & 15;
            gload_lds16(xg + (long)(nb + nn) * 8192 + k * 512 + lane * 8,
                        lds + nn * 16384 + k * 1024);
        } else {
            const int cc = c - 32, nn = cc >> 3, k = cc & 7;
            gload_lds16(Wt + (long)(nb + nn) * 4096 + k * 512 + lane * 8,
                        lds + 32768 + nn * 8192 + k * 1024);
        }
    }
    __syncthreads();

    const int node = nb + (wid >> 1);
    const int bh   = wid & 1;
    const char* xl = lds + (wid >> 1) * 16384;
    const char* wlp = lds + 32768 + (wid >> 1) * 8192;

    f32x4 acc[4][4];
#pragma unroll
    for (int m = 0; m < 4; ++m)
#pragma unroll
        for (int n = 0; n < 4; ++n) acc[m][n] = f32x4{0.f, 0.f, 0.f, 0.f};

#pragma unroll
    for (int s = 0; s < 2; ++s) {
        const int kb = s * 4 + (lane >> 4);
        bf16x8 a[4], b[4];
#pragma unroll
        for (int m = 0; m < 4; ++m) {
            const int brow = bh * 64 + m * 16 + (lane & 15);
            a[m] = *(const bf16x8*)(xl + brow * 128 + ((kb ^ (lane & 7)) << 4));
        }
#pragma unroll
        for (int n = 0; n < 4; ++n)
            b[n] = *(const bf16x8*)(wlp + kb * 1024 + (n * 16 + (lane & 15)) * 16);
#pragma unroll
        for (int m = 0; m < 4; ++m)
#pragma unroll
            for (int n = 0; n < 4; ++n)
                acc[m][n] = __builtin_amdgcn_mfma_f32_16x16x32_bf16(a[m], b[n], acc[m][n], 0, 0, 0);
    }

#pragma unroll
    for (int n = 0; n < 4; ++n) {
        const int o = n * 16 + (lane & 15);
        const float bv = bias[node * 64 + o];
#pragma unroll
        for (int m = 0; m < 4; ++m) {
            const int b0 = bh * 64 + m * 16 + (lane >> 4) * 4;
#pragma unroll
            for (int r = 0; r < 4; ++r)
                out[(long)(b0 + r) * 65536 + node * 64 + o] = acc[m][n][r] + bv;
        }
    }
}

extern "C" void kernel_launch(void* const* d_in, const int* in_sizes, int n_in,
                              void* d_out, int out_size, void* d_ws, size_t ws_size,
                              hipStream_t stream) {
    const float* x     = (const float*)d_in[0];
    const float* emb   = (const float*)d_in[1];
    const float* wpool = (const float*)d_in[2];
    const float* bpool = (const float*)d_in[3];
    float* out = (float*)d_out;

    char* ws = (char*)d_ws;
    unsigned short* sup  = (unsigned short*)(ws);                        // 2 MiB
    unsigned short* xbt  = (unsigned short*)(ws + (2u  << 20));          // 16 MiB
    unsigned short* Wt   = (unsigned short*)(ws + (18u << 20));          // 8 MiB
    float*          bias = (float*)         (ws + (26u << 20));          // 256 KiB
    unsigned short* xg   = (unsigned short*)(ws + (27u << 20));          // 16 MiB
    (void)in_sizes; (void)n_in; (void)out_size; (void)ws_size;

    k_prep<<<dim3(3200), dim3(256), 0, stream>>>(x, emb, wpool, bpool,
                                                 xbt, sup, Wt, bias);
    k_agg<<<dim3(8, 64), dim3(256), 0, stream>>>(sup, xbt, xg);
    k_out<<<dim3(512), dim3(256), 0, stream>>>(xg, Wt, bias, out);
}

// Round 14
// 56.991 us; speedup vs baseline: 1.2751x; 1.0978x over previous
//
#include <hip/hip_runtime.h>

#define N_NODES 1024
#define BATCH   128
#define E_DIM   16

// S / xbt panel format (bf16, per 128-row x 1024-k panel, 256KB):
//   elem(row, k) at (k>>6)*8192 + ((k>>3)&7)*1024 + row*8 + (k&7)
// Wt per-node tiled: n*4096 + kblk*512 + o*8 + e   (i = kblk*8+e)
// xg layout (node-major, swizzled): short off =
//   node*8192 + b*64 + ((ib ^ (b&7))*8 + e)   where i = ib*8+e

typedef __attribute__((ext_vector_type(8))) short bf16x8;
typedef __attribute__((ext_vector_type(4))) float f32x4;
typedef __attribute__((ext_vector_type(16))) float f32x16;

__device__ __forceinline__ unsigned short f2bf(float f) {
    union { float f; unsigned int u; } v; v.f = f;
    unsigned int u = v.u;
    u += 0x7FFFu + ((u >> 16) & 1u);
    return (unsigned short)(u >> 16);
}

__device__ __forceinline__ void gload_lds16(const void* g, void* l) {
    __builtin_amdgcn_global_load_lds(
        (const __attribute__((address_space(1))) unsigned int*)g,
        (__attribute__((address_space(3))) unsigned int*)l, 16, 0, 0);
}

// ---------------- X: xbt transpose, register-only, low-VGPR -----------------
__global__ __launch_bounds__(256) void k_xt(const float* __restrict__ x,
                                            unsigned short* __restrict__ xbt) {
    const int bid = blockIdx.x;
    const int t = threadIdx.x;
    const int b = bid >> 4, kt64 = bid & 15;
    unsigned short* dstp = xbt + (long)(b >> 1) * 131072 + kt64 * 8192
                         + (b & 1) * 512;          // + kblk*1024 + c*8
#pragma unroll
    for (int h = 0; h < 2; ++h) {
        const int g = h * 256 + t;                 // 0..511
        const int kblk = g >> 6, c = g & 63;
        const float* s = x + ((long)b * 1024 + kt64 * 64 + kblk * 8) * 64 + c;
        bf16x8 r;
#pragma unroll
        for (int e = 0; e < 8; ++e) r[e] = (short)f2bf(s[e * 64]);
        *(bf16x8*)(dstp + kblk * 1024 + c * 8) = r;
    }
}

// ---------------- W/S: weights (4 nodes/blk) + supports fused ---------------
// grid: [0,256) weights | [256,1280) supports
__global__ __launch_bounds__(256) void k_wsup(const float* __restrict__ emb,
                                              const float* __restrict__ wpool,
                                              const float* __restrict__ bpool,
                                              unsigned short* __restrict__ sup,
                                              unsigned short* __restrict__ Wt,
                                              float* __restrict__ bias) {
    __shared__ float sm[132];
    const int bid = blockIdx.x;
    const int t = threadIdx.x;

    if (bid < 256) {
        // ---- weights: 4 nodes/block, register-direct, barrier-free ----
        float (*en4)[E_DIM] = (float(*)[E_DIM])sm;
        const int n0 = bid * 4;
        if (t < 64) en4[t >> 4][t & 15] = emb[(n0 + (t >> 4)) * E_DIM + (t & 15)];
        __syncthreads();
        const int o = t & 63;
#pragma unroll
        for (int p = 0; p < 2; ++p) {
            const int kblk = p * 4 + (t >> 6);
            float w[4][8];
#pragma unroll
            for (int nn = 0; nn < 4; ++nn)
#pragma unroll
                for (int e = 0; e < 8; ++e) w[nn][e] = 0.f;
            for (int ed = 0; ed < E_DIM; ++ed) {
                float v[8];
#pragma unroll
                for (int e = 0; e < 8; ++e)
                    v[e] = wpool[ed * 4096 + (kblk * 8 + e) * 64 + o];  // 256B coalesced
#pragma unroll
                for (int nn = 0; nn < 4; ++nn)
#pragma unroll
                    for (int e = 0; e < 8; ++e)
                        w[nn][e] = fmaf(en4[nn][ed], v[e], w[nn][e]);
            }
#pragma unroll
            for (int nn = 0; nn < 4; ++nn) {
                bf16x8 r;
#pragma unroll
                for (int e = 0; e < 8; ++e) r[e] = (short)f2bf(w[nn][e]);
                *(bf16x8*)(Wt + (long)(n0 + nn) * 4096 + kblk * 512 + o * 8) = r;
            }
        }
        {   // bias: 4 nodes x 64 o
            const int nn = t >> 6, oo = t & 63;
            float s = 0.f;
#pragma unroll
            for (int e = 0; e < E_DIM; ++e) s = fmaf(en4[nn][e], bpool[e * 64 + oo], s);
            bias[(n0 + nn) * 64 + oo] = s;
        }
    } else {
        // ---- supports: softmax(relu(emb emb^T)) row, tiled (R6) ----
        float* en  = sm;
        float* red = sm + 128;
        const int n = bid - 256;
        if (t < E_DIM) en[t] = emb[n * E_DIM + t];
        __syncthreads();
        float sc[4];
        float mx = -1e30f;
#pragma unroll
        for (int r = 0; r < 4; ++r) {
            const float* em = &emb[(r * 256 + t) * E_DIM];
            float s = 0.f;
#pragma unroll
            for (int e = 0; e < E_DIM; ++e) s = fmaf(en[e], em[e], s);
            s = fmaxf(s, 0.f);
            sc[r] = s;
            mx = fmaxf(mx, s);
        }
#pragma unroll
        for (int o = 32; o > 0; o >>= 1) mx = fmaxf(mx, __shfl_xor(mx, o));
        if ((t & 63) == 0) red[t >> 6] = mx;
        __syncthreads();
        mx = fmaxf(fmaxf(red[0], red[1]), fmaxf(red[2], red[3]));
        float sum = 0.f;
#pragma unroll
        for (int r = 0; r < 4; ++r) { sc[r] = __expf(sc[r] - mx); sum += sc[r]; }
#pragma unroll
        for (int o = 32; o > 0; o >>= 1) sum += __shfl_xor(sum, o);
        __syncthreads();
        if ((t & 63) == 0) red[t >> 6] = sum;
        __syncthreads();
        sum = red[0] + red[1] + red[2] + red[3];
        const float inv = 1.f / sum;
#pragma unroll
        for (int r = 0; r < 4; ++r) {
            const int m = r * 256 + t;
            const int off = (n >> 7) * 131072 + (m >> 6) * 8192 + ((m >> 3) & 7) * 1024
                          + (n & 127) * 8 + (m & 7);
            sup[off] = f2bf(sc[r] * inv);
        }
    }
}

// ---------------- D: xg = S @ X, 128x128, BK=32, 1-barrier/iter (R10) -------
__global__ __launch_bounds__(256, 2) void k_agg(const unsigned short* __restrict__ S,
                                                const unsigned short* __restrict__ Bt,
                                                unsigned short* __restrict__ xg) {
    __shared__ __align__(16) char lds[65536];   // 4 buffers x 16KB
    const int t = threadIdx.x;
    const int lane = t & 63, wid = t >> 6;

    const int hw   = blockIdx.x + 8 * blockIdx.y;      // grid (8, 64)
    const int work = (hw & 7) * 64 + (hw >> 3);
    const int n0 = (work & 7) * 128, j0 = (work >> 3) * 128;
    const int wr = wid >> 1, wc = wid & 1;

    f32x16 acc[2][2];
#pragma unroll
    for (int m = 0; m < 2; ++m)
#pragma unroll
        for (int n = 0; n < 2; ++n)
#pragma unroll
            for (int r = 0; r < 16; ++r) acc[m][n][r] = 0.f;

    const unsigned short* pA = S  + (n0 >> 7) * 131072 + lane * 8;
    const unsigned short* pB = Bt + (j0 >> 7) * 131072 + lane * 8;
    const unsigned short* sp[4];
    int doff[4];
#pragma unroll
    for (int i = 0; i < 4; ++i) {
        const int c = wid * 4 + i;
        if (c < 8) { sp[i] = pA + c * 512;       doff[i] = c * 1024; }
        else       { sp[i] = pB + (c - 8) * 512; doff[i] = 8192 + (c - 8) * 1024; }
    }
#define STAGE(kt) do {                                                   \
        char* buf_ = lds + ((kt) & 3) * 16384;                           \
        const int ko_ = (kt) * 4096;                                     \
        gload_lds16(sp[0] + ko_, buf_ + doff[0]);                        \
        gload_lds16(sp[1] + ko_, buf_ + doff[1]);                        \
        gload_lds16(sp[2] + ko_, buf_ + doff[2]);                        \
        gload_lds16(sp[3] + ko_, buf_ + doff[3]);                        \
    } while (0)

    int aoff[2], boff[2];
#pragma unroll
    for (int m = 0; m < 2; ++m)
        aoff[m] = (lane >> 5) * 2048 + (wr * 64 + m * 32 + (lane & 31)) * 16;
#pragma unroll
    for (int n = 0; n < 2; ++n)
        boff[n] = 8192 + (lane >> 5) * 2048 + (wc * 64 + n * 32 + (lane & 31)) * 16;

    STAGE(0); STAGE(1);
    for (int kt = 0; kt < 32; ++kt) {
        if (kt < 31) asm volatile("s_waitcnt vmcnt(4)" ::: "memory");
        else         asm volatile("s_waitcnt vmcnt(0)" ::: "memory");
        __builtin_amdgcn_s_barrier();
        asm volatile("" ::: "memory");
        __builtin_amdgcn_sched_barrier(0);
        if (kt + 2 < 32) STAGE(kt + 2);
        const char* cur = lds + (kt & 3) * 16384;
        __builtin_amdgcn_s_setprio(1);
#pragma unroll
        for (int s = 0; s < 2; ++s) {
            bf16x8 a[2], b[2];
#pragma unroll
            for (int m = 0; m < 2; ++m) a[m] = *(const bf16x8*)(cur + s * 4096 + aoff[m]);
#pragma unroll
            for (int n = 0; n < 2; ++n) b[n] = *(const bf16x8*)(cur + s * 4096 + boff[n]);
#pragma unroll
            for (int m = 0; m < 2; ++m)
#pragma unroll
                for (int n = 0; n < 2; ++n)
                    acc[m][n] = __builtin_amdgcn_mfma_f32_32x32x16_bf16(a[m], b[n], acc[m][n], 0, 0, 0);
        }
        __builtin_amdgcn_s_setprio(0);
        asm volatile("" ::: "memory");
        __builtin_amdgcn_sched_barrier(0);
    }
#undef STAGE
    __syncthreads();

    // epilogue: acc -> LDS bf16 [128 row][128 col] swizzled -> node-major xg
    char* lb = lds;
#pragma unroll
    for (int m = 0; m < 2; ++m) {
#pragma unroll
        for (int n = 0; n < 2; ++n) {
            const int col  = wc * 64 + n * 32 + (lane & 31);
            const int rowb = wr * 64 + m * 32 + 4 * (lane >> 5);
#pragma unroll
            for (int r = 0; r < 16; ++r) {
                const int row = rowb + (r & 3) + 8 * (r >> 2);
                *(unsigned short*)(lb + row * 256 + ((col * 2) ^ ((row & 7) << 4))) =
                    f2bf(acc[m][n][r]);
            }
        }
    }
    __syncthreads();
    const int b0 = j0 >> 6;
#pragma unroll
    for (int i = 0; i < 8; ++i) {
        const int idx = i * 256 + t;
        const int row = idx >> 4, cc = idx & 15;
        bf16x8 v = *(const bf16x8*)(lb + row * 256 + ((cc * 16) ^ ((row & 7) << 4)));
        const int b = b0 + (cc >> 3);
        const long dst = (long)(n0 + row) * 8192 + b * 64 + ((cc & 7) ^ (b & 7)) * 8;
        *(bf16x8*)(xg + dst) = v;
    }
}

// ---------------- E: out, 2 nodes per block ---------------------------------
__global__ __launch_bounds__(256) void k_out(const unsigned short* __restrict__ xg,
                                             const unsigned short* __restrict__ Wt,
                                             const float* __restrict__ bias,
                                             float* __restrict__ out) {
    __shared__ __align__(16) char lds[49152];
    const int t = threadIdx.x, lane = t & 63, wid = t >> 6;
    const int nb = blockIdx.x * 2;
#pragma unroll
    for (int i = 0; i < 12; ++i) {
        const int c = wid * 12 + i;            // 0..47 contiguous 1KB chunks
        if (c < 32) {
            const int nn = c >> 4, k = c & 15;
            gload_lds16(xg + (long)(nb + nn) * 8192 + k * 512 + lane * 8,
                        lds + nn * 16384 + k * 1024);
        } else {
            const int cc = c - 32, nn = cc >> 3, k = cc & 7;
            gload_lds16(Wt + (long)(nb + nn) * 4096 + k * 512 + lane * 8,
                        lds + 32768 + nn * 8192 + k * 1024);
        }
    }
    __syncthreads();

    const int node = nb + (wid >> 1);
    const int bh   = wid & 1;
    const char* xl = lds + (wid >> 1) * 16384;
    const char* wlp = lds + 32768 + (wid >> 1) * 8192;

    f32x4 acc[4][4];
#pragma unroll
    for (int m = 0; m < 4; ++m)
#pragma unroll
        for (int n = 0; n < 4; ++n) acc[m][n] = f32x4{0.f, 0.f, 0.f, 0.f};

#pragma unroll
    for (int s = 0; s < 2; ++s) {
        const int kb = s * 4 + (lane >> 4);
        bf16x8 a[4], b[4];
#pragma unroll
        for (int m = 0; m < 4; ++m) {
            const int brow = bh * 64 + m * 16 + (lane & 15);
            a[m] = *(const bf16x8*)(xl + brow * 128 + ((kb ^ (lane & 7)) << 4));
        }
#pragma unroll
        for (int n = 0; n < 4; ++n)
            b[n] = *(const bf16x8*)(wlp + kb * 1024 + (n * 16 + (lane & 15)) * 16);
#pragma unroll
        for (int m = 0; m < 4; ++m)
#pragma unroll
            for (int n = 0; n < 4; ++n)
                acc[m][n] = __builtin_amdgcn_mfma_f32_16x16x32_bf16(a[m], b[n], acc[m][n], 0, 0, 0);
    }

#pragma unroll
    for (int n = 0; n < 4; ++n) {
        const int o = n * 16 + (lane & 15);
        const float bv = bias[node * 64 + o];
#pragma unroll
        for (int m = 0; m < 4; ++m) {
            const int b0 = bh * 64 + m * 16 + (lane >> 4) * 4;
#pragma unroll
            for (int r = 0; r < 4; ++r)
                out[(long)(b0 + r) * 65536 + node * 64 + o] = acc[m][n][r] + bv;
        }
    }
}

extern "C" void kernel_launch(void* const* d_in, const int* in_sizes, int n_in,
                              void* d_out, int out_size, void* d_ws, size_t ws_size,
                              hipStream_t stream) {
    const float* x     = (const float*)d_in[0];
    const float* emb   = (const float*)d_in[1];
    const float* wpool = (const float*)d_in[2];
    const float* bpool = (const float*)d_in[3];
    float* out = (float*)d_out;

    char* ws = (char*)d_ws;
    unsigned short* sup  = (unsigned short*)(ws);                        // 2 MiB
    unsigned short* xbt  = (unsigned short*)(ws + (2u  << 20));          // 16 MiB
    unsigned short* Wt   = (unsigned short*)(ws + (18u << 20));          // 8 MiB
    float*          bias = (float*)         (ws + (26u << 20));          // 256 KiB
    unsigned short* xg   = (unsigned short*)(ws + (27u << 20));          // 16 MiB
    (void)in_sizes; (void)n_in; (void)out_size; (void)ws_size;

    k_xt<<<dim3(2048), dim3(256), 0, stream>>>(x, xbt);
    k_wsup<<<dim3(1280), dim3(256), 0, stream>>>(emb, wpool, bpool, sup, Wt, bias);
    k_agg<<<dim3(8, 64), dim3(256), 0, stream>>>(sup, xbt, xg);
    k_out<<<dim3(512), dim3(256), 0, stream>>>(xg, Wt, bias, out);
}